// Round 14
// baseline (54.312 us; speedup 1.0000x reference)
//
#include <hip/hip_runtime.h>
#include <hip/hip_bf16.h>
#include <math.h>

#define NEG 0.1f
#define EPSV 1e-8f

constexpr int D = 1024;

typedef __bf16 bf16x8 __attribute__((ext_vector_type(8)));
typedef __bf16 bf16x4 __attribute__((ext_vector_type(4)));
typedef float  f32x4  __attribute__((ext_vector_type(4)));

__device__ __forceinline__ bf16x8 cvt8(float4 a, float4 b) {
    bf16x8 r;
    r[0] = (__bf16)a.x; r[1] = (__bf16)a.y; r[2] = (__bf16)a.z; r[3] = (__bf16)a.w;
    r[4] = (__bf16)b.x; r[5] = (__bf16)b.y; r[6] = (__bf16)b.z; r[7] = (__bf16)b.w;
    return r;
}

// async global->LDS, 16B/lane; LDS dest = wave-uniform base + lane*16
__device__ __forceinline__ void gld_lds16(const __bf16* g, __bf16* l) {
    __builtin_amdgcn_global_load_lds(
        (__attribute__((address_space(1))) void*)(size_t)(const void*)g,
        (__attribute__((address_space(3))) void*)l,
        16, 0, 0);
}

// ---------- fused conversion, BK=32 swizzle key = (row>>1)&3 (R13) ----------
// blocks [0,3328):   W x2 (g<262144) then img rows t<36 only (no pad writes).
// blocks [3328,3840): cap -> bf16 swizzled (t<len only) + per-(c,q) partial sums.
__global__ __launch_bounds__(256)
void convert_all(const float* __restrict__ Wvt, const float* __restrict__ Wvi,
                 const float* __restrict__ img, const float* __restrict__ cap,
                 const int* __restrict__ lens,
                 __bf16* __restrict__ wtb, __bf16* __restrict__ wib,
                 __bf16* __restrict__ imgb, __bf16* __restrict__ capb,
                 float* __restrict__ cappart)
{
    const int bid = blockIdx.x;
    if (bid < 3328) {
        int g = bid * 256 + threadIdx.x;
        if (g < 262144) {
            // W path: dst slot sl holds orig slot sl^((e>>1)&3) within 32-chunk
            const float* src = (g < 131072) ? Wvt : Wvi;
            __bf16*      dst = (g < 131072) ? wtb : wib;
            g &= 131071;
            const int e  = g >> 7;
            const int sl = g & 127;                  // 8-elem slot
            const int ch = sl >> 2, si = sl & 3;
            const int ss = (ch << 2) | (si ^ ((e >> 1) & 3));
            const float* p = src + (size_t)e * D + ss * 8;
            *(bf16x8*)(dst + (size_t)e * D + sl * 8) =
                cvt8(*(const float4*)p, *(const float4*)(p + 4));
        } else {
            // img path: rows t<36 only; dst row = c*64+t, key (t>>1)&3
            const int gg = g - 262144;               // < 589824 = 128*36*128
            const int Rd = gg >> 7, sl = gg & 127;   // Rd = c*36+t
            const int c  = Rd / 36, t = Rd - c * 36;
            const int ch = sl >> 2, si = sl & 3;
            const int s2 = (ch << 2) | (si ^ ((t >> 1) & 3));
            const float* p = img + (size_t)Rd * D + s2 * 8;
            *(bf16x8*)(imgb + (size_t)(c * 64 + t) * D + sl * 8) =
                cvt8(*(const float4*)p, *(const float4*)(p + 4));
        }
    } else {
        // cap path: (c, quarter) converts live rows + masked partial sums
        const int cb2 = bid - 3328;                  // 0..511
        const int c = cb2 >> 2, q = cb2 & 3;
        const int col = threadIdx.x * 4;
        const int cb = col & ~31;                    // 32-elem chunk base
        const int u  = (col >> 3) & 3;               // slot in chunk
        const int lo = col & 7;
        const int len = lens[c];
        const float* src = cap + (size_t)c * 64 * D + col;
        __bf16* drow = capb + (size_t)c * 64 * D;
        float4 acc = make_float4(0.f, 0.f, 0.f, 0.f);
        #pragma unroll
        for (int tt = 0; tt < 16; ++tt) {
            const int t = q * 16 + tt;
            if (t < len) {                           // dead rows: no read, no write
                float4 v = *(const float4*)(src + (size_t)t * D);
                acc.x += v.x; acc.y += v.y; acc.z += v.z; acc.w += v.w;
                bf16x4 w;
                w[0] = (__bf16)v.x; w[1] = (__bf16)v.y;
                w[2] = (__bf16)v.z; w[3] = (__bf16)v.w;
                *(bf16x4*)(drow + (size_t)t * D + cb + ((u ^ ((t >> 1) & 3)) << 3) + lo) = w;
            }
        }
        *(float4*)(cappart + ((size_t)q * 128 + c) * D + col) = acc;
    }
}

// ---------- K-loop, ring-of-5, depth-3 prefetch, per-wave vmem count U ----------
// U = 2 (B only) / 3 (B + A rows[+0,16)) / 4 (B + both A halves).
// Unit s issued at step s-3; steady-state vmcnt(3U) keeps 3 units in flight.
// Ring-5 makes depth-3 WAR-safe with ONE barrier/step: issue(s+3) targets
// buf (s+3)%5 = (s-2)%5, whose readers finished before the step s-1 barrier.
template<int U>
__device__ __forceinline__ void kloop_run(
    __bf16* sm, const __bf16* aS, const __bf16* bS, int dOff,
    int wm, int wn, int r16, int skew, const bool (&mact)[8],
    f32x4 (&acc)[8][4])
{
    __bf16* Ab[5] = { sm, sm + 8192, sm + 16384, sm + 24576, sm + 32768 };
    __bf16* Bb[5] = { sm + 40960, sm + 49152, sm + 57344, sm + 65536, sm + 73728 };

    auto issueU = [&](int s, __bf16* Ad, __bf16* Bd) {
        if constexpr (U >= 3)
            gld_lds16(aS + (size_t)s * 32,            Ad + dOff);
        if constexpr (U >= 4)
            gld_lds16(aS + (size_t)(16 * D + s * 32), Ad + dOff + 512);
        gld_lds16(bS + (size_t)s * 32,            Bd + dOff);
        gld_lds16(bS + (size_t)(16 * D + s * 32), Bd + dOff + 512);
    };
    auto compute = [&](const __bf16* Ac, const __bf16* Bc) {
        bf16x8 bf[4];
        #pragma unroll
        for (int ni = 0; ni < 4; ++ni)
            bf[ni] = *(const bf16x8*)&Bc[(wn * 64 + ni * 16 + r16) * 32 + skew];
        #pragma unroll
        for (int mi = 0; mi < 8; ++mi) {
            if (!mact[mi]) continue;
            bf16x8 af = *(const bf16x8*)&Ac[(wm * 128 + mi * 16 + r16) * 32 + skew];
            #pragma unroll
            for (int ni = 0; ni < 4; ++ni)
                acc[mi][ni] = __builtin_amdgcn_mfma_f32_16x16x32_bf16(
                    af, bf[ni], acc[mi][ni], 0, 0, 0);
        }
    };

    issueU(0, Ab[0], Bb[0]);
    issueU(1, Ab[1], Bb[1]);
    issueU(2, Ab[2], Bb[2]);
    #pragma unroll
    for (int s = 0; s < 29; ++s) {       // full unroll -> static %5 and vmcnt
        issueU(s + 3, Ab[(s + 3) % 5], Bb[(s + 3) % 5]);
        asm volatile("s_waitcnt vmcnt(%0)" :: "n"(3 * U) : "memory");
        asm volatile("s_barrier" ::: "memory");
        compute(Ab[s % 5], Bb[s % 5]);
    }
    asm volatile("s_waitcnt vmcnt(%0)" :: "n"(2 * U) : "memory");
    asm volatile("s_barrier" ::: "memory");
    compute(Ab[4], Bb[4]);               // s=29
    asm volatile("s_waitcnt vmcnt(%0)" :: "n"(U) : "memory");
    asm volatile("s_barrier" ::: "memory");
    compute(Ab[0], Bb[0]);               // s=30
    asm volatile("s_waitcnt vmcnt(0)" ::: "memory");
    asm volatile("s_barrier" ::: "memory");
    compute(Ab[1], Bb[1]);               // s=31
}

// ---------- 8-wave 256x256 GEMM body ----------
template<bool IMG>
__device__ __forceinline__ void gemm_body(
    const __bf16* __restrict__ Asrc, const __bf16* __restrict__ Wsw,
    const float* __restrict__ bias, const int* __restrict__ lens,
    float scale, float* __restrict__ out, int mb, int nb, __bf16* sm)
{
    const int tid  = threadIdx.x;
    const int wid  = tid >> 6;     // 0..7
    const int lane = tid & 63;
    const int r16  = lane & 15;
    const int kg   = lane >> 4;
    const int wm   = wid >> 2;     // 0..1 (M half)
    const int wn   = wid & 3;      // 0..3 (N quarter)
    const int e0   = nb * 256;
    const int bglobal = mb * 4;

    int lb[2];
    #pragma unroll
    for (int g = 0; g < 2; ++g) {
        const int b = bglobal + wm * 2 + g;
        lb[g] = IMG ? 36 : (lens[b] < 64 ? lens[b] : 64);
    }
    bool mact[8];
    #pragma unroll
    for (int mi = 0; mi < 8; ++mi)
        mact[mi] = ((mi & 3) * 16) < lb[mi >> 2];

    const __bf16* aS = Asrc + (size_t)(mb * 256 + wid * 32 + (lane >> 2)) * D
                     + (lane & 3) * 8;
    const __bf16* bS = Wsw  + (size_t)(e0 + wid * 32 + (lane >> 2)) * D
                     + (lane & 3) * 8;
    const int dOff = wid * 1024;
    const int skew = (kg ^ ((r16 >> 1) & 3)) << 3;

    f32x4 acc[8][4];
    #pragma unroll
    for (int mi = 0; mi < 8; ++mi)
        #pragma unroll
        for (int ni = 0; ni < 4; ++ni)
            acc[mi][ni] = (f32x4){0.f, 0.f, 0.f, 0.f};

    // per-wave live A rows: wave covers rows [(wid&1)*32, +32) of its batch
    const int Lb   = IMG ? 36
                         : (lens[bglobal + (wid >> 1)] < 64 ? lens[bglobal + (wid >> 1)] : 64);
    const int roff = (wid & 1) * 32;
    const int u    = 2 + (Lb > roff ? 1 : 0) + (Lb > roff + 16 ? 1 : 0);

    if (u == 4)      kloop_run<4>(sm, aS, bS, dOff, wm, wn, r16, skew, mact, acc);
    else if (u == 3) kloop_run<3>(sm, aS, bS, dOff, wm, wn, r16, skew, mact, acc);
    else             kloop_run<2>(sm, aS, bS, dOff, wm, wn, r16, skew, mact, acc);

    // ---- epilogue: bias + leaky + row mask + reduce over rows ----
    float bv[4];
    #pragma unroll
    for (int ni = 0; ni < 4; ++ni) bv[ni] = bias[e0 + wn * 64 + ni * 16 + r16];

    float part[2][4];
    #pragma unroll
    for (int g = 0; g < 2; ++g)
        #pragma unroll
        for (int ni = 0; ni < 4; ++ni) part[g][ni] = 0.f;

    #pragma unroll
    for (int mi = 0; mi < 8; ++mi) {
        const int g = mi >> 2;
        #pragma unroll
        for (int j = 0; j < 4; ++j) {
            const int t = (mi & 3) * 16 + kg * 4 + j;
            if (t < lb[g]) {
                #pragma unroll
                for (int ni = 0; ni < 4; ++ni) {
                    float v = acc[mi][ni][j] + bv[ni];
                    v = v > 0.f ? v : NEG * v;     // leaky before mask (ref order)
                    part[g][ni] += v;
                }
            }
        }
    }
    #pragma unroll
    for (int g = 0; g < 2; ++g)
        #pragma unroll
        for (int ni = 0; ni < 4; ++ni) {
            part[g][ni] += __shfl_xor(part[g][ni], 16, 64);
            part[g][ni] += __shfl_xor(part[g][ni], 32, 64);
        }

    float v0, v1;
    if      (kg == 0) { v0 = part[0][0]; v1 = part[0][1]; }
    else if (kg == 1) { v0 = part[0][2]; v1 = part[0][3]; }
    else if (kg == 2) { v0 = part[1][0]; v1 = part[1][1]; }
    else              { v0 = part[1][2]; v1 = part[1][3]; }
    const int g  = kg >> 1, nh = kg & 1;
    const int batch = bglobal + wm * 2 + g;
    float* orow = out + (size_t)batch * D + e0 + wn * 64 + nh * 32 + r16;
    orow[0]  = scale * v0;
    orow[16] = scale * v1;
}

__global__ __launch_bounds__(512, 2)
void vsum_union(const __bf16* __restrict__ capb, const __bf16* __restrict__ wtb,
                const float* __restrict__ bvt,
                const __bf16* __restrict__ imgb, const __bf16* __restrict__ wib,
                const float* __restrict__ bvi,
                const int* __restrict__ lens, float scale,
                float* __restrict__ ctxbar, float* __restrict__ vbar)
{
    extern __shared__ __bf16 sm[];
    const int bid = blockIdx.x;
    const int xcd = bid & 7;
    const int mb  = bid >> 3;          // 0..31
    const int nb  = xcd >> 1;          // 0..3
    if (!(xcd & 1))
        gemm_body<false>(capb, wtb, bvt, lens,  scale, ctxbar, mb, nb, sm);
    else
        gemm_body<true >(imgb, wib, bvi, nullptr, scale, vbar,  mb, nb, sm);
}

// ---------- sims stage 1: pair partials + per-row scalars (768 blocks) ----------
__global__ __launch_bounds__(256)
void sims_sp(const float* __restrict__ ctxbar, const float* __restrict__ vbar,
             const float* __restrict__ cappart,
             float* __restrict__ part1, float* __restrict__ part2,
             float* __restrict__ scal)   // [0,128)=s3 [128,256)=s4 [256,384)=s6 [384,512)=s5
{
    const int b = blockIdx.x;
    const int tid = threadIdx.x;
    if (b < 512) {
        const int kb = b >> 6;
        const int i0 = ((b & 63) >> 3) * 16;
        const int c0 = (b & 7) * 16;
        const int k0 = kb * 128;
        __shared__ float Cx[16][132], Vb[16][132], Cs[16][132];
        #pragma unroll
        for (int p = 0; p < 2; ++p) {
            const int idx = tid + p * 256;       // 0..511
            const int row = idx >> 5;
            const int c4  = (idx & 31) * 4;
            *(float4*)&Cx[row][c4] = *(const float4*)(ctxbar + (size_t)(c0 + row) * D + k0 + c4);
            *(float4*)&Vb[row][c4] = *(const float4*)(vbar   + (size_t)(i0 + row) * D + k0 + c4);
            const float* cp = cappart + (size_t)(c0 + row) * D + k0 + c4;
            float4 a0 = *(const float4*)cp;
            float4 a1 = *(const float4*)(cp + (size_t)128 * D);
            float4 a2 = *(const float4*)(cp + (size_t)256 * D);
            float4 a3 = *(const float4*)(cp + (size_t)384 * D);
            a0.x += a1.x + a2.x + a3.x; a0.y += a1.y + a2.y + a3.y;
            a0.z += a1.z + a2.z + a3.z; a0.w += a1.w + a2.w + a3.w;
            *(float4*)&Cs[row][c4] = a0;
        }
        __syncthreads();
        const int tx = tid & 15, ty = tid >> 4;
        float s1 = 0.f, s2 = 0.f;
        #pragma unroll 8
        for (int k4 = 0; k4 < 32; ++k4) {
            float4 xv = *(const float4*)&Vb[ty][k4 * 4];
            float4 xc = *(const float4*)&Cx[tx][k4 * 4];
            float4 xp = *(const float4*)&Cs[tx][k4 * 4];
            s1 += xc.x * xv.x + xc.y * xv.y + xc.z * xv.z + xc.w * xv.w;
            s2 += xv.x * xp.x + xv.y * xp.y + xv.z * xp.z + xv.w * xp.w;
        }
        const int o = (i0 + ty) * 128 + (c0 + tx);
        part1[kb * 16384 + o] = s1;
        part2[kb * 16384 + o] = s2;
    } else if (b < 640) {
        const int c = b - 512;
        const int col = tid * 4;
        const float* cp = cappart + (size_t)c * D + col;
        float4 a0 = *(const float4*)cp;
        float4 a1 = *(const float4*)(cp + (size_t)128 * D);
        float4 a2 = *(const float4*)(cp + (size_t)256 * D);
        float4 a3 = *(const float4*)(cp + (size_t)384 * D);
        a0.x += a1.x + a2.x + a3.x; a0.y += a1.y + a2.y + a3.y;
        a0.z += a1.z + a2.z + a3.z; a0.w += a1.w + a2.w + a3.w;
        float4 cx = *(const float4*)(ctxbar + (size_t)c * D + col);
        float s3 = cx.x * a0.x + cx.y * a0.y + cx.z * a0.z + cx.w * a0.w;
        float s4 = cx.x * cx.x + cx.y * cx.y + cx.z * cx.z + cx.w * cx.w;
        float s6 = a0.x * a0.x + a0.y * a0.y + a0.z * a0.z + a0.w * a0.w;
        #pragma unroll
        for (int o = 32; o > 0; o >>= 1) {
            s3 += __shfl_xor(s3, o, 64);
            s4 += __shfl_xor(s4, o, 64);
            s6 += __shfl_xor(s6, o, 64);
        }
        __shared__ float red[3][4];
        if ((tid & 63) == 0) {
            red[0][tid >> 6] = s3; red[1][tid >> 6] = s4; red[2][tid >> 6] = s6;
        }
        __syncthreads();
        if (tid == 0) {
            scal[c]       = red[0][0] + red[0][1] + red[0][2] + red[0][3];
            scal[128 + c] = red[1][0] + red[1][1] + red[1][2] + red[1][3];
            scal[256 + c] = red[2][0] + red[2][1] + red[2][2] + red[2][3];
        }
    } else {
        const int i = b - 640;
        const int col = tid * 4;
        float4 vb = *(const float4*)(vbar + (size_t)i * D + col);
        float s5 = vb.x * vb.x + vb.y * vb.y + vb.z * vb.z + vb.w * vb.w;
        #pragma unroll
        for (int o = 32; o > 0; o >>= 1) s5 += __shfl_xor(s5, o, 64);
        __shared__ float red1[4];
        if ((tid & 63) == 0) red1[tid >> 6] = s5;
        __syncthreads();
        if (tid == 0) scal[384 + i] = red1[0] + red1[1] + red1[2] + red1[3];
    }
}

// ---------- sims stage 2: finalize (64 blocks, 1 output/thread) ----------
__global__ __launch_bounds__(256)
void sims_final(const float* __restrict__ part1, const float* __restrict__ part2,
                const float* __restrict__ scal, const int* __restrict__ lens,
                const float* __restrict__ gptr, float* __restrict__ out)
{
    const int o = blockIdx.x * 256 + threadIdx.x;   // 0..16383
    const int c = o & 127;
    float s1 = 0.f, s2 = 0.f;
    #pragma unroll
    for (int kb = 0; kb < 8; ++kb) {
        s1 += part1[kb * 16384 + o];
        s2 += part2[kb * 16384 + o];
    }
    const float g  = *gptr;
    const float s3 = scal[c], s4 = scal[128 + c], s6 = scal[256 + c];
    const float s5 = scal[384 + (o >> 7)];
    const float lenf = (float)lens[c];
    const float f = 1.f / (sqrtf(s6) + EPSV * lenf);
    const float num = (g * s3 + s2) * f;
    const float den = sqrtf(g * g * s4 + 2.f * g * s1 + s5) + EPSV;
    out[o] = num / den;
}

extern "C" void kernel_launch(void* const* d_in, const int* in_sizes, int n_in,
                              void* d_out, int out_size, void* d_ws, size_t ws_size,
                              hipStream_t stream)
{
    const float* img  = (const float*)d_in[0];   // [128,36,1024]
    const float* cap  = (const float*)d_in[1];   // [128,64,1024]
    const int*   lens = (const int*)  d_in[2];   // [128]
    const float* Wvi  = (const float*)d_in[7];   // [1024,1024]
    const float* bvi  = (const float*)d_in[8];
    const float* Wvt  = (const float*)d_in[9];   // [1024,1024]
    const float* bvt  = (const float*)d_in[10];
    const float* gamma = (const float*)d_in[11];
    // Wq/bq/Wk/bk/alpha/beta dead: softmax then mean over same axis == 1/R.

    float* out = (float*)d_out;

    // ws: wtb 2M | wib 2M | capb 16M | imgb 16M | ctx .5 | vb .5 | cappart 2M |
    //     part1 .5M | part2 .5M | scal 2K
    __bf16* wtb  = (__bf16*)d_ws;
    __bf16* wib  = wtb + (size_t)1024 * 1024;
    __bf16* capb = wib + (size_t)1024 * 1024;            // 128*64*1024
    __bf16* imgb = capb + (size_t)128 * 64 * 1024;       // 128*64*1024 (36-63 unwritten)
    float* ctxbar  = (float*)(imgb + (size_t)128 * 64 * 1024);
    float* vbar    = ctxbar + 128 * 1024;
    float* cappart = vbar   + 128 * 1024;                // 4*128*1024
    float* part1   = cappart + 4 * 128 * 1024;           // 8*16384
    float* part2   = part1 + 8 * 16384;                  // 8*16384
    float* scal    = part2 + 8 * 16384;                  // 512

    const float scale = 1.f / 36.f;      // attn_mean == 1/R exactly; also v_img mean
    dim3 blk(256);

    hipFuncSetAttribute((const void*)vsum_union,
                        hipFuncAttributeMaxDynamicSharedMemorySize, 163840);

    convert_all<<<dim3(3840), blk, 0, stream>>>(Wvt, Wvi, img, cap, lens,
                                                wtb, wib, imgb, capb, cappart);
    vsum_union<<<dim3(256), dim3(512), 163840, stream>>>(capb, wtb, bvt,
                                                         imgb, wib, bvi,
                                                         lens, scale, ctxbar, vbar);
    sims_sp<<<dim3(768), blk, 0, stream>>>(ctxbar, vbar, cappart, part1, part2, scal);
    sims_final<<<dim3(64), blk, 0, stream>>>(part1, part2, scal, lens, gamma, out);
}

// Round 16
// 52.993 us; speedup vs baseline: 1.0249x; 1.0249x over previous
//
#include <hip/hip_runtime.h>
#include <hip/hip_bf16.h>
#include <math.h>

#define NEG 0.1f
#define EPSV 1e-8f

constexpr int D = 1024;

typedef __bf16 bf16x8 __attribute__((ext_vector_type(8)));
typedef __bf16 bf16x4 __attribute__((ext_vector_type(4)));
typedef float  f32x4  __attribute__((ext_vector_type(4)));

__device__ __forceinline__ bf16x8 cvt8(float4 a, float4 b) {
    bf16x8 r;
    r[0] = (__bf16)a.x; r[1] = (__bf16)a.y; r[2] = (__bf16)a.z; r[3] = (__bf16)a.w;
    r[4] = (__bf16)b.x; r[5] = (__bf16)b.y; r[6] = (__bf16)b.z; r[7] = (__bf16)b.w;
    return r;
}

// async global->LDS, 16B/lane; LDS dest = wave-uniform base + lane*16
__device__ __forceinline__ void gld_lds16(const __bf16* g, __bf16* l) {
    __builtin_amdgcn_global_load_lds(
        (__attribute__((address_space(1))) void*)(size_t)(const void*)g,
        (__attribute__((address_space(3))) void*)l,
        16, 0, 0);
}

// ---------- fused conversion, BK=32 swizzle key = (row>>1)&3 (R13) ----------
// blocks [0,3328):   W x2 (g<262144) then img rows t<36 only (no pad writes).
// blocks [3328,3840): cap -> bf16 swizzled (t<len only) + per-(c,q) partial sums.
__global__ __launch_bounds__(256)
void convert_all(const float* __restrict__ Wvt, const float* __restrict__ Wvi,
                 const float* __restrict__ img, const float* __restrict__ cap,
                 const int* __restrict__ lens,
                 __bf16* __restrict__ wtb, __bf16* __restrict__ wib,
                 __bf16* __restrict__ imgb, __bf16* __restrict__ capb,
                 float* __restrict__ cappart)
{
    const int bid = blockIdx.x;
    if (bid < 3328) {
        int g = bid * 256 + threadIdx.x;
        if (g < 262144) {
            // W path: dst slot sl holds orig slot sl^((e>>1)&3) within 32-chunk
            const float* src = (g < 131072) ? Wvt : Wvi;
            __bf16*      dst = (g < 131072) ? wtb : wib;
            g &= 131071;
            const int e  = g >> 7;
            const int sl = g & 127;                  // 8-elem slot
            const int ch = sl >> 2, si = sl & 3;
            const int ss = (ch << 2) | (si ^ ((e >> 1) & 3));
            const float* p = src + (size_t)e * D + ss * 8;
            *(bf16x8*)(dst + (size_t)e * D + sl * 8) =
                cvt8(*(const float4*)p, *(const float4*)(p + 4));
        } else {
            // img path: rows t<36 only; dst row = c*64+t, key (t>>1)&3
            const int gg = g - 262144;               // < 589824 = 128*36*128
            const int Rd = gg >> 7, sl = gg & 127;   // Rd = c*36+t
            const int c  = Rd / 36, t = Rd - c * 36;
            const int ch = sl >> 2, si = sl & 3;
            const int s2 = (ch << 2) | (si ^ ((t >> 1) & 3));
            const float* p = img + (size_t)Rd * D + s2 * 8;
            *(bf16x8*)(imgb + (size_t)(c * 64 + t) * D + sl * 8) =
                cvt8(*(const float4*)p, *(const float4*)(p + 4));
        }
    } else {
        // cap path: (c, quarter) converts live rows + masked partial sums
        const int cb2 = bid - 3328;                  // 0..511
        const int c = cb2 >> 2, q = cb2 & 3;
        const int col = threadIdx.x * 4;
        const int cb = col & ~31;                    // 32-elem chunk base
        const int u  = (col >> 3) & 3;               // slot in chunk
        const int lo = col & 7;
        const int len = lens[c];
        const float* src = cap + (size_t)c * 64 * D + col;
        __bf16* drow = capb + (size_t)c * 64 * D;
        float4 acc = make_float4(0.f, 0.f, 0.f, 0.f);
        #pragma unroll
        for (int tt = 0; tt < 16; ++tt) {
            const int t = q * 16 + tt;
            if (t < len) {                           // dead rows: no read, no write
                float4 v = *(const float4*)(src + (size_t)t * D);
                acc.x += v.x; acc.y += v.y; acc.z += v.z; acc.w += v.w;
                bf16x4 w;
                w[0] = (__bf16)v.x; w[1] = (__bf16)v.y;
                w[2] = (__bf16)v.z; w[3] = (__bf16)v.w;
                *(bf16x4*)(drow + (size_t)t * D + cb + ((u ^ ((t >> 1) & 3)) << 3) + lo) = w;
            }
        }
        *(float4*)(cappart + ((size_t)q * 128 + c) * D + col) = acc;
    }
}

// ---------- K-loop, ring-of-4, depth-2, per-wave vmem count U (2..4) ----------
// U = 2 (B only) / 3 (B + A rows[+0,16)) / 4 (B + both A halves).
// Unit s issued at step s-2; steady-state vmcnt(2U) keeps 2 units in flight.
// Ring-4 is the minimum WAR-safe ring at depth-2 with one barrier/step.
template<int U>
__device__ __forceinline__ void kloop_run(
    __bf16* sm, const __bf16* aS, const __bf16* bS, int dOff,
    int wm, int wn, int r16, int skew, const bool (&mact)[8],
    f32x4 (&acc)[8][4])
{
    __bf16* Ab[4] = { sm,         sm + 8192,  sm + 16384, sm + 24576 };
    __bf16* Bb[4] = { sm + 32768, sm + 40960, sm + 49152, sm + 57344 };

    auto issueU = [&](int s, __bf16* Ad, __bf16* Bd) {
        if constexpr (U >= 3)
            gld_lds16(aS + (size_t)s * 32,            Ad + dOff);
        if constexpr (U >= 4)
            gld_lds16(aS + (size_t)(16 * D + s * 32), Ad + dOff + 512);
        gld_lds16(bS + (size_t)s * 32,            Bd + dOff);
        gld_lds16(bS + (size_t)(16 * D + s * 32), Bd + dOff + 512);
    };
    auto compute = [&](const __bf16* Ac, const __bf16* Bc) {
        bf16x8 bf[4];
        #pragma unroll
        for (int ni = 0; ni < 4; ++ni)
            bf[ni] = *(const bf16x8*)&Bc[(wn * 64 + ni * 16 + r16) * 32 + skew];
        #pragma unroll
        for (int mi = 0; mi < 8; ++mi) {
            if (!mact[mi]) continue;
            bf16x8 af = *(const bf16x8*)&Ac[(wm * 128 + mi * 16 + r16) * 32 + skew];
            #pragma unroll
            for (int ni = 0; ni < 4; ++ni)
                acc[mi][ni] = __builtin_amdgcn_mfma_f32_16x16x32_bf16(
                    af, bf[ni], acc[mi][ni], 0, 0, 0);
        }
    };

    issueU(0, Ab[0], Bb[0]);
    issueU(1, Ab[1], Bb[1]);
    #pragma unroll 4
    for (int s = 0; s < 28; ++s) {
        issueU(s + 2, Ab[(s + 2) & 3], Bb[(s + 2) & 3]);
        asm volatile("s_waitcnt vmcnt(%0)" :: "n"(2 * U) : "memory");
        asm volatile("s_barrier" ::: "memory");
        compute(Ab[s & 3], Bb[s & 3]);
    }
    issueU(30, Ab[2], Bb[2]);
    asm volatile("s_waitcnt vmcnt(%0)" :: "n"(2 * U) : "memory");
    asm volatile("s_barrier" ::: "memory");
    compute(Ab[0], Bb[0]);
    issueU(31, Ab[3], Bb[3]);
    asm volatile("s_waitcnt vmcnt(%0)" :: "n"(2 * U) : "memory");
    asm volatile("s_barrier" ::: "memory");
    compute(Ab[1], Bb[1]);
    asm volatile("s_waitcnt vmcnt(%0)" :: "n"(U) : "memory");
    asm volatile("s_barrier" ::: "memory");
    compute(Ab[2], Bb[2]);
    asm volatile("s_waitcnt vmcnt(0)" ::: "memory");
    asm volatile("s_barrier" ::: "memory");
    compute(Ab[3], Bb[3]);
}

// ---------- 8-wave 256x256 GEMM body ----------
template<bool IMG>
__device__ __forceinline__ void gemm_body(
    const __bf16* __restrict__ Asrc, const __bf16* __restrict__ Wsw,
    const float* __restrict__ bias, const int* __restrict__ lens,
    float scale, float* __restrict__ out, int mb, int nb, __bf16* sm)
{
    const int tid  = threadIdx.x;
    const int wid  = tid >> 6;     // 0..7
    const int lane = tid & 63;
    const int r16  = lane & 15;
    const int kg   = lane >> 4;
    const int wm   = wid >> 2;     // 0..1 (M half)
    const int wn   = wid & 3;      // 0..3 (N quarter)
    const int e0   = nb * 256;
    const int bglobal = mb * 4;

    int lb[2];
    #pragma unroll
    for (int g = 0; g < 2; ++g) {
        const int b = bglobal + wm * 2 + g;
        lb[g] = IMG ? 36 : (lens[b] < 64 ? lens[b] : 64);
    }
    bool mact[8];
    #pragma unroll
    for (int mi = 0; mi < 8; ++mi)
        mact[mi] = ((mi & 3) * 16) < lb[mi >> 2];

    const __bf16* aS = Asrc + (size_t)(mb * 256 + wid * 32 + (lane >> 2)) * D
                     + (lane & 3) * 8;
    const __bf16* bS = Wsw  + (size_t)(e0 + wid * 32 + (lane >> 2)) * D
                     + (lane & 3) * 8;
    const int dOff = wid * 1024;
    const int skew = (kg ^ ((r16 >> 1) & 3)) << 3;

    f32x4 acc[8][4];
    #pragma unroll
    for (int mi = 0; mi < 8; ++mi)
        #pragma unroll
        for (int ni = 0; ni < 4; ++ni)
            acc[mi][ni] = (f32x4){0.f, 0.f, 0.f, 0.f};

    // per-wave live A rows: wave covers rows [(wid&1)*32, +32) of its batch
    const int Lb   = IMG ? 36
                         : (lens[bglobal + (wid >> 1)] < 64 ? lens[bglobal + (wid >> 1)] : 64);
    const int roff = (wid & 1) * 32;
    const int u    = 2 + (Lb > roff ? 1 : 0) + (Lb > roff + 16 ? 1 : 0);

    if (u == 4)      kloop_run<4>(sm, aS, bS, dOff, wm, wn, r16, skew, mact, acc);
    else if (u == 3) kloop_run<3>(sm, aS, bS, dOff, wm, wn, r16, skew, mact, acc);
    else             kloop_run<2>(sm, aS, bS, dOff, wm, wn, r16, skew, mact, acc);

    // ---- epilogue: bias + leaky + row mask + reduce over rows ----
    float bv[4];
    #pragma unroll
    for (int ni = 0; ni < 4; ++ni) bv[ni] = bias[e0 + wn * 64 + ni * 16 + r16];

    float part[2][4];
    #pragma unroll
    for (int g = 0; g < 2; ++g)
        #pragma unroll
        for (int ni = 0; ni < 4; ++ni) part[g][ni] = 0.f;

    #pragma unroll
    for (int mi = 0; mi < 8; ++mi) {
        const int g = mi >> 2;
        #pragma unroll
        for (int j = 0; j < 4; ++j) {
            const int t = (mi & 3) * 16 + kg * 4 + j;
            if (t < lb[g]) {
                #pragma unroll
                for (int ni = 0; ni < 4; ++ni) {
                    float v = acc[mi][ni][j] + bv[ni];
                    v = v > 0.f ? v : NEG * v;     // leaky before mask (ref order)
                    part[g][ni] += v;
                }
            }
        }
    }
    #pragma unroll
    for (int g = 0; g < 2; ++g)
        #pragma unroll
        for (int ni = 0; ni < 4; ++ni) {
            part[g][ni] += __shfl_xor(part[g][ni], 16, 64);
            part[g][ni] += __shfl_xor(part[g][ni], 32, 64);
        }

    float v0, v1;
    if      (kg == 0) { v0 = part[0][0]; v1 = part[0][1]; }
    else if (kg == 1) { v0 = part[0][2]; v1 = part[0][3]; }
    else if (kg == 2) { v0 = part[1][0]; v1 = part[1][1]; }
    else              { v0 = part[1][2]; v1 = part[1][3]; }
    const int g  = kg >> 1, nh = kg & 1;
    const int batch = bglobal + wm * 2 + g;
    float* orow = out + (size_t)batch * D + e0 + wn * 64 + nh * 32 + r16;
    orow[0]  = scale * v0;
    orow[16] = scale * v1;
}

__global__ __launch_bounds__(512, 2)
void vsum_union(const __bf16* __restrict__ capb, const __bf16* __restrict__ wtb,
                const float* __restrict__ bvt,
                const __bf16* __restrict__ imgb, const __bf16* __restrict__ wib,
                const float* __restrict__ bvi,
                const int* __restrict__ lens, float scale,
                float* __restrict__ ctxbar, float* __restrict__ vbar)
{
    extern __shared__ __bf16 sm[];
    const int bid = blockIdx.x;
    const int xcd = bid & 7;
    const int mb  = bid >> 3;          // 0..31
    const int nb  = xcd >> 1;          // 0..3
    if (!(xcd & 1))
        gemm_body<false>(capb, wtb, bvt, lens,  scale, ctxbar, mb, nb, sm);
    else
        gemm_body<true >(imgb, wib, bvi, nullptr, scale, vbar,  mb, nb, sm);
}

// ---------- sims stage 1: pair partials + per-row scalars (768 blocks) ----------
__global__ __launch_bounds__(256)
void sims_sp(const float* __restrict__ ctxbar, const float* __restrict__ vbar,
             const float* __restrict__ cappart,
             float* __restrict__ part1, float* __restrict__ part2,
             float* __restrict__ scal)   // [0,128)=s3 [128,256)=s4 [256,384)=s6 [384,512)=s5
{
    const int b = blockIdx.x;
    const int tid = threadIdx.x;
    if (b < 512) {
        const int kb = b >> 6;
        const int i0 = ((b & 63) >> 3) * 16;
        const int c0 = (b & 7) * 16;
        const int k0 = kb * 128;
        __shared__ float Cx[16][132], Vb[16][132], Cs[16][132];
        #pragma unroll
        for (int p = 0; p < 2; ++p) {
            const int idx = tid + p * 256;       // 0..511
            const int row = idx >> 5;
            const int c4  = (idx & 31) * 4;
            *(float4*)&Cx[row][c4] = *(const float4*)(ctxbar + (size_t)(c0 + row) * D + k0 + c4);
            *(float4*)&Vb[row][c4] = *(const float4*)(vbar   + (size_t)(i0 + row) * D + k0 + c4);
            const float* cp = cappart + (size_t)(c0 + row) * D + k0 + c4;
            float4 a0 = *(const float4*)cp;
            float4 a1 = *(const float4*)(cp + (size_t)128 * D);
            float4 a2 = *(const float4*)(cp + (size_t)256 * D);
            float4 a3 = *(const float4*)(cp + (size_t)384 * D);
            a0.x += a1.x + a2.x + a3.x; a0.y += a1.y + a2.y + a3.y;
            a0.z += a1.z + a2.z + a3.z; a0.w += a1.w + a2.w + a3.w;
            *(float4*)&Cs[row][c4] = a0;
        }
        __syncthreads();
        const int tx = tid & 15, ty = tid >> 4;
        float s1 = 0.f, s2 = 0.f;
        #pragma unroll 8
        for (int k4 = 0; k4 < 32; ++k4) {
            float4 xv = *(const float4*)&Vb[ty][k4 * 4];
            float4 xc = *(const float4*)&Cx[tx][k4 * 4];
            float4 xp = *(const float4*)&Cs[tx][k4 * 4];
            s1 += xc.x * xv.x + xc.y * xv.y + xc.z * xv.z + xc.w * xv.w;
            s2 += xv.x * xp.x + xv.y * xp.y + xv.z * xp.z + xv.w * xp.w;
        }
        const int o = (i0 + ty) * 128 + (c0 + tx);
        part1[kb * 16384 + o] = s1;
        part2[kb * 16384 + o] = s2;
    } else if (b < 640) {
        const int c = b - 512;
        const int col = tid * 4;
        const float* cp = cappart + (size_t)c * D + col;
        float4 a0 = *(const float4*)cp;
        float4 a1 = *(const float4*)(cp + (size_t)128 * D);
        float4 a2 = *(const float4*)(cp + (size_t)256 * D);
        float4 a3 = *(const float4*)(cp + (size_t)384 * D);
        a0.x += a1.x + a2.x + a3.x; a0.y += a1.y + a2.y + a3.y;
        a0.z += a1.z + a2.z + a3.z; a0.w += a1.w + a2.w + a3.w;
        float4 cx = *(const float4*)(ctxbar + (size_t)c * D + col);
        float s3 = cx.x * a0.x + cx.y * a0.y + cx.z * a0.z + cx.w * a0.w;
        float s4 = cx.x * cx.x + cx.y * cx.y + cx.z * cx.z + cx.w * cx.w;
        float s6 = a0.x * a0.x + a0.y * a0.y + a0.z * a0.z + a0.w * a0.w;
        #pragma unroll
        for (int o = 32; o > 0; o >>= 1) {
            s3 += __shfl_xor(s3, o, 64);
            s4 += __shfl_xor(s4, o, 64);
            s6 += __shfl_xor(s6, o, 64);
        }
        __shared__ float red[3][4];
        if ((tid & 63) == 0) {
            red[0][tid >> 6] = s3; red[1][tid >> 6] = s4; red[2][tid >> 6] = s6;
        }
        __syncthreads();
        if (tid == 0) {
            scal[c]       = red[0][0] + red[0][1] + red[0][2] + red[0][3];
            scal[128 + c] = red[1][0] + red[1][1] + red[1][2] + red[1][3];
            scal[256 + c] = red[2][0] + red[2][1] + red[2][2] + red[2][3];
        }
    } else {
        const int i = b - 640;
        const int col = tid * 4;
        float4 vb = *(const float4*)(vbar + (size_t)i * D + col);
        float s5 = vb.x * vb.x + vb.y * vb.y + vb.z * vb.z + vb.w * vb.w;
        #pragma unroll
        for (int o = 32; o > 0; o >>= 1) s5 += __shfl_xor(s5, o, 64);
        __shared__ float red1[4];
        if ((tid & 63) == 0) red1[tid >> 6] = s5;
        __syncthreads();
        if (tid == 0) scal[384 + i] = red1[0] + red1[1] + red1[2] + red1[3];
    }
}

// ---------- sims stage 2: finalize (64 blocks, 1 output/thread) ----------
__global__ __launch_bounds__(256)
void sims_final(const float* __restrict__ part1, const float* __restrict__ part2,
                const float* __restrict__ scal, const int* __restrict__ lens,
                const float* __restrict__ gptr, float* __restrict__ out)
{
    const int o = blockIdx.x * 256 + threadIdx.x;   // 0..16383
    const int c = o & 127;
    float s1 = 0.f, s2 = 0.f;
    #pragma unroll
    for (int kb = 0; kb < 8; ++kb) {
        s1 += part1[kb * 16384 + o];
        s2 += part2[kb * 16384 + o];
    }
    const float g  = *gptr;
    const float s3 = scal[c], s4 = scal[128 + c], s6 = scal[256 + c];
    const float s5 = scal[384 + (o >> 7)];
    const float lenf = (float)lens[c];
    const float f = 1.f / (sqrtf(s6) + EPSV * lenf);
    const float num = (g * s3 + s2) * f;
    const float den = sqrtf(g * g * s4 + 2.f * g * s1 + s5) + EPSV;
    out[o] = num / den;
}

extern "C" void kernel_launch(void* const* d_in, const int* in_sizes, int n_in,
                              void* d_out, int out_size, void* d_ws, size_t ws_size,
                              hipStream_t stream)
{
    const float* img  = (const float*)d_in[0];   // [128,36,1024]
    const float* cap  = (const float*)d_in[1];   // [128,64,1024]
    const int*   lens = (const int*)  d_in[2];   // [128]
    const float* Wvi  = (const float*)d_in[7];   // [1024,1024]
    const float* bvi  = (const float*)d_in[8];
    const float* Wvt  = (const float*)d_in[9];   // [1024,1024]
    const float* bvt  = (const float*)d_in[10];
    const float* gamma = (const float*)d_in[11];
    // Wq/bq/Wk/bk/alpha/beta dead: softmax then mean over same axis == 1/R.

    float* out = (float*)d_out;

    // ws: wtb 2M | wib 2M | capb 16M | imgb 16M | ctx .5 | vb .5 | cappart 2M |
    //     part1 .5M | part2 .5M | scal 2K
    __bf16* wtb  = (__bf16*)d_ws;
    __bf16* wib  = wtb + (size_t)1024 * 1024;
    __bf16* capb = wib + (size_t)1024 * 1024;            // 128*64*1024
    __bf16* imgb = capb + (size_t)128 * 64 * 1024;       // 128*64*1024 (36-63 unwritten)
    float* ctxbar  = (float*)(imgb + (size_t)128 * 64 * 1024);
    float* vbar    = ctxbar + 128 * 1024;
    float* cappart = vbar   + 128 * 1024;                // 4*128*1024
    float* part1   = cappart + 4 * 128 * 1024;           // 8*16384
    float* part2   = part1 + 8 * 16384;                  // 8*16384
    float* scal    = part2 + 8 * 16384;                  // 512

    const float scale = 1.f / 36.f;      // attn_mean == 1/R exactly; also v_img mean
    dim3 blk(256);

    hipFuncSetAttribute((const void*)vsum_union,
                        hipFuncAttributeMaxDynamicSharedMemorySize, 131072);

    convert_all<<<dim3(3840), blk, 0, stream>>>(Wvt, Wvi, img, cap, lens,
                                                wtb, wib, imgb, capb, cappart);
    vsum_union<<<dim3(256), dim3(512), 131072, stream>>>(capb, wtb, bvt,
                                                         imgb, wib, bvi,
                                                         lens, scale, ctxbar, vbar);
    sims_sp<<<dim3(768), blk, 0, stream>>>(ctxbar, vbar, cappart, part1, part2, scal);
    sims_final<<<dim3(64), blk, 0, stream>>>(part1, part2, scal, lens, gamma, out);
}